// Round 6
// baseline (258.258 us; speedup 1.0000x reference)
//
#include <hip/hip_runtime.h>
#include <math.h>

// GCN, aggregate-then-transform, fully fused:
//   k_bucket: CSR counting-sort per 256-node bucket + dinv + u1 = x*dinv
//   k_layer1: per-node gather-agg of u1 (18f) + @W1 + relu -> u2 (=h1*dinv)
//   k_layer2: per-node gather-agg of u2 (32f) + @W2 + relu + FC(64->2) + log_softmax
// eb packed: (src<<8) | (dst & 255)  -- src < 2^17 so 25 bits total.

#define TPB 256
#define BSH 8                 // 256 nodes per bucket
#define BNODES 256
#define MAXBUCK 512
#define CH 8192               // edges per partition block
#define NPW 8                 // nodes per wave in layer kernels

__global__ void k_zero(int* __restrict__ p, int n) {
    int i = blockIdx.x * blockDim.x + threadIdx.x;
    if (i < n) p[i] = 0;
}

__global__ void k_bhist(const int* __restrict__ dst, int* __restrict__ bhist,
                        int E, int nbuck) {
    __shared__ int lh[MAXBUCK];
    for (int i = threadIdx.x; i < nbuck; i += TPB) lh[i] = 0;
    __syncthreads();
    for (int e = blockIdx.x * TPB + threadIdx.x; e < E; e += gridDim.x * TPB)
        atomicAdd(&lh[dst[e] >> BSH], 1);
    __syncthreads();
    for (int i = threadIdx.x; i < nbuck; i += TPB)
        if (lh[i]) atomicAdd(&bhist[i], lh[i]);
}

__global__ void k_bscan(const int* __restrict__ bhist, int* __restrict__ boff,
                        int* __restrict__ bcursor, int nbuck, int E) {
    __shared__ int sm[TPB];
    int t = threadIdx.x;
    int carry = 0;
    for (int base = 0; base < nbuck; base += TPB) {
        int i = base + t;
        int v = (i < nbuck) ? bhist[i] : 0;
        sm[t] = v;
        __syncthreads();
        for (int off = 1; off < TPB; off <<= 1) {
            int x = (t >= off) ? sm[t - off] : 0;
            __syncthreads();
            sm[t] += x;
            __syncthreads();
        }
        if (i < nbuck) { boff[i] = carry + sm[t] - v; bcursor[i] = boff[i]; }
        carry += sm[TPB - 1];
        __syncthreads();
    }
    if (t == 0) boff[nbuck] = E;
}

__global__ void k_part(const int* __restrict__ src, const int* __restrict__ dst,
                       int* __restrict__ bcursor, int* __restrict__ eb,
                       int E, int nbuck) {
    __shared__ int lh[MAXBUCK];
    __shared__ int lbase[MAXBUCK];
    int t = threadIdx.x;
    int chunk0 = blockIdx.x * CH;
    int end = min(chunk0 + CH, E);
    for (int i = t; i < nbuck; i += TPB) lh[i] = 0;
    __syncthreads();
    for (int e = chunk0 + t; e < end; e += TPB)
        atomicAdd(&lh[dst[e] >> BSH], 1);
    __syncthreads();
    for (int i = t; i < nbuck; i += TPB) {
        int c = lh[i];
        lbase[i] = c ? atomicAdd(&bcursor[i], c) : 0;
        lh[i] = 0;
    }
    __syncthreads();
    for (int e = chunk0 + t; e < end; e += TPB) {
        int d = dst[e];
        int b = d >> BSH;
        int r = atomicAdd(&lh[b], 1);
        eb[lbase[b] + r] = (src[e] << BSH) | (d & (BNODES - 1));
    }
}

// per bucket: LDS counting sort -> csr_src/row_start/dinv, plus u1 = x*dinv
__global__ void k_bucket(const int* __restrict__ eb, const int* __restrict__ boff,
                         const float* __restrict__ x,
                         int* __restrict__ csr_src, int* __restrict__ row_start,
                         float* __restrict__ dinv, float* __restrict__ u1,
                         int n, int nbuck) {
    __shared__ int lcnt[BNODES];
    __shared__ int lscan[BNODES];
    __shared__ float ldinv[BNODES];
    int b = blockIdx.x;
    int t = threadIdx.x;
    int node0 = b << BSH;
    int beg = boff[b], end = boff[b + 1];
    lcnt[t] = 0;
    __syncthreads();
    for (int i = beg + t; i < end; i += TPB)
        atomicAdd(&lcnt[eb[i] & (BNODES - 1)], 1);
    __syncthreads();
    int v = lcnt[t];
    lscan[t] = v;
    __syncthreads();
    for (int off = 1; off < TPB; off <<= 1) {
        int xx = (t >= off) ? lscan[t - off] : 0;
        __syncthreads();
        lscan[t] += xx;
        __syncthreads();
    }
    int excl = lscan[t] - v;
    int node = node0 + t;
    float dv = rsqrtf(1.0f + (float)v);
    ldinv[t] = dv;
    if (node < n) {
        row_start[node] = beg + excl;
        dinv[node] = dv;
    }
    if (b == nbuck - 1 && t == 0) row_start[n] = end;
    __syncthreads();
    lcnt[t] = excl;
    __syncthreads();
    for (int i = beg + t; i < end; i += TPB) {
        int e = eb[i];
        int p = atomicAdd(&lcnt[e & (BNODES - 1)], 1);
        csr_src[beg + p] = e >> BSH;
    }
    // u1 rows for this bucket (coalesced)
    int nn = min(BNODES, n - node0);
    int tot = nn * 18;
    const float* xb = x + (size_t)node0 * 18;
    float* ub = u1 + (size_t)node0 * 18;
    for (int i = t; i < tot; i += TPB) {
        int nl = i / 18;
        ub[i] = xb[i] * ldinv[nl];
    }
}

// layer 1 fused: wave per node (NPW serial). 8 edges/iter via float2 gathers.
// lane: g=lane>>3 (edge in group), q=lane&7 (float2 at f=2q); q==0 lanes also
// fetch f=16..17. Transform: all lanes redundantly compute f=lane&31 (<32).
__global__ void k_layer1(const float* __restrict__ u1, const int* __restrict__ row_start,
                         const int* __restrict__ csr, const float* __restrict__ dinv,
                         const float* __restrict__ W1, const float* __restrict__ b1,
                         float* __restrict__ u2, int n) {
    int lane = threadIdx.x & 63;
    int g = lane >> 3, q = lane & 7;
    int wid = __builtin_amdgcn_readfirstlane((int)(threadIdx.x >> 6));
    int wave = blockIdx.x * (TPB / 64) + wid;
    int f = lane & 31;
    float w1r[18];
#pragma unroll
    for (int k = 0; k < 18; ++k) w1r[k] = W1[k * 32 + f];
    float b1v = b1[f];
    int node0 = wave * NPW;
    for (int r = 0; r < NPW; ++r) {
        int node = node0 + r;
        if (node >= n) return;
        int beg = row_start[node];
        int T = row_start[node + 1] - beg + 1;   // + self edge (entry 0)
        float amx = 0.f, amy = 0.f, aex = 0.f, aey = 0.f;
        int it = (T + 7) >> 3;
        for (int i = 0; i < it; ++i) {
            int base = i * 8;
            int idx_l = node;
            if (lane < 8) {
                int e = base + lane;
                if (e > 0 && e < T) idx_l = csr[beg + e - 1];
            }
            int srcn = __shfl(idx_l, g, 64);
            bool valid = (base + g) < T;
            const float* rp = u1 + (size_t)srcn * 18;
            float2 vm = *(const float2*)(rp + 2 * q);
            if (valid) { amx += vm.x; amy += vm.y; }
            if (q == 0) {
                float2 ve = *(const float2*)(rp + 16);
                if (valid) { aex += ve.x; aey += ve.y; }
            }
        }
#pragma unroll
        for (int m = 8; m < 64; m <<= 1) {
            amx += __shfl_xor(amx, m, 64);
            amy += __shfl_xor(amy, m, 64);
            aex += __shfl_xor(aex, m, 64);
            aey += __shfl_xor(aey, m, 64);
        }
        float a = 0.f;
#pragma unroll
        for (int k = 0; k < 16; ++k) {
            float rk = __shfl((k & 1) ? amy : amx, k >> 1, 64);
            a = fmaf(rk, w1r[k], a);
        }
        a = fmaf(__shfl(aex, 0, 64), w1r[16], a);
        a = fmaf(__shfl(aey, 0, 64), w1r[17], a);
        float di = dinv[node];
        if (lane < 32) u2[(size_t)node * 32 + f] = fmaxf(fmaf(di, a, b1v), 0.f) * di;
    }
}

// layer 2 fused: wave per node (NPW serial). 8 edges/iter via float4 gathers.
// lane: g=lane>>3, q=lane&7 (float4 at f=4q... wait q<8 covers 32f). Transform
// f_out=lane (64 outputs of W2), then FC(64->2) + log_softmax.
__global__ void k_layer2(const float* __restrict__ u2, const int* __restrict__ row_start,
                         const int* __restrict__ csr, const float* __restrict__ dinv,
                         const float* __restrict__ W2, const float* __restrict__ b2,
                         const float* __restrict__ Wfc, const float* __restrict__ bfc,
                         float* __restrict__ out, int n) {
    int lane = threadIdx.x & 63;
    int g = lane >> 3, q = lane & 7;
    int wid = __builtin_amdgcn_readfirstlane((int)(threadIdx.x >> 6));
    int wave = blockIdx.x * (TPB / 64) + wid;
    float w2r[32];
#pragma unroll
    for (int k = 0; k < 32; ++k) w2r[k] = W2[k * 64 + lane];
    float b2v = b2[lane];
    float wf0 = Wfc[lane * 2 + 0], wf1 = Wfc[lane * 2 + 1];
    float bf0 = bfc[0], bf1 = bfc[1];
    int node0 = wave * NPW;
    for (int r = 0; r < NPW; ++r) {
        int node = node0 + r;
        if (node >= n) return;
        int beg = row_start[node];
        int T = row_start[node + 1] - beg + 1;   // + self
        float ax = 0.f, ay = 0.f, az = 0.f, aw = 0.f;
        int it = (T + 7) >> 3;
        for (int i = 0; i < it; ++i) {
            int base = i * 8;
            int idx_l = node;
            if (lane < 8) {
                int e = base + lane;
                if (e > 0 && e < T) idx_l = csr[beg + e - 1];
            }
            int srcn = __shfl(idx_l, g, 64);
            bool valid = (base + g) < T;
            float4 v = *(const float4*)(u2 + (size_t)srcn * 32 + q * 4);
            if (valid) { ax += v.x; ay += v.y; az += v.z; aw += v.w; }
        }
#pragma unroll
        for (int m = 8; m < 64; m <<= 1) {
            ax += __shfl_xor(ax, m, 64);
            ay += __shfl_xor(ay, m, 64);
            az += __shfl_xor(az, m, 64);
            aw += __shfl_xor(aw, m, 64);
        }
        float a = 0.f;
#pragma unroll
        for (int k = 0; k < 32; ++k) {
            float rk;
            int sl = k >> 2;
            switch (k & 3) {
                case 0:  rk = __shfl(ax, sl, 64); break;
                case 1:  rk = __shfl(ay, sl, 64); break;
                case 2:  rk = __shfl(az, sl, 64); break;
                default: rk = __shfl(aw, sl, 64); break;
            }
            a = fmaf(rk, w2r[k], a);
        }
        float v = fmaxf(fmaf(dinv[node], a, b2v), 0.f);
        float l0 = v * wf0;
        float l1 = v * wf1;
#pragma unroll
        for (int off = 32; off >= 1; off >>= 1) {
            l0 += __shfl_xor(l0, off, 64);
            l1 += __shfl_xor(l1, off, 64);
        }
        if (lane == 0) {
            l0 += bf0;
            l1 += bf1;
            float m2 = fmaxf(l0, l1);
            float lse = m2 + logf(expf(l0 - m2) + expf(l1 - m2));
            out[node * 2 + 0] = l0 - lse;
            out[node * 2 + 1] = l1 - lse;
        }
    }
}

extern "C" void kernel_launch(void* const* d_in, const int* in_sizes, int n_in,
                              void* d_out, int out_size, void* d_ws, size_t ws_size,
                              hipStream_t stream) {
    const float* x   = (const float*)d_in[0];
    const int*   ei  = (const int*)d_in[1];
    const float* W1  = (const float*)d_in[2];
    const float* b1  = (const float*)d_in[3];
    const float* W2  = (const float*)d_in[4];
    const float* b2  = (const float*)d_in[5];
    const float* Wfc = (const float*)d_in[6];
    const float* bfc = (const float*)d_in[7];
    float* out = (float*)d_out;

    const int n = in_sizes[0] / 18;
    const int E = in_sizes[1] / 2;
    const int* src = ei;
    const int* dst = ei + E;
    const int nbuck = (n + BNODES - 1) >> BSH;

    // ws (4B elems): bhist[nbuck] | boff[nbuck+1] | bcursor[nbuck]
    //  | row_start[n+1] | dinv[n] | csr_src[E] | eb[E] | u1[n*18] | u2[n*32]
    char* w = (char*)d_ws;
    int*   bhist     = (int*)w;    w += (size_t)nbuck * 4;
    int*   boff      = (int*)w;    w += (size_t)(nbuck + 1) * 4;
    int*   bcursor   = (int*)w;    w += (size_t)nbuck * 4;
    int*   row_start = (int*)w;    w += (size_t)(n + 1) * 4;
    float* dinv      = (float*)w;  w += (size_t)n * 4;
    int*   csr_src   = (int*)w;    w += (size_t)E * 4;
    int*   eb        = (int*)w;    w += (size_t)E * 4;
    float* u1        = (float*)w;  w += (size_t)n * 18 * 4;
    float* u2        = (float*)w;  w += (size_t)n * 32 * 4;

    auto blocks = [](long long work) { return (int)((work + TPB - 1) / TPB); };

    // ---- CSR build: bucketed counting sort ----
    k_zero<<<blocks(nbuck), TPB, 0, stream>>>(bhist, nbuck);
    k_bhist<<<256, TPB, 0, stream>>>(dst, bhist, E, nbuck);
    k_bscan<<<1, TPB, 0, stream>>>(bhist, boff, bcursor, nbuck, E);
    k_part<<<(E + CH - 1) / CH, TPB, 0, stream>>>(src, dst, bcursor, eb, E, nbuck);
    k_bucket<<<nbuck, TPB, 0, stream>>>(eb, boff, x, csr_src, row_start, dinv, u1, n, nbuck);

    const int wavesL = (n + NPW - 1) / NPW;
    const int blocksL = (wavesL + (TPB / 64) - 1) / (TPB / 64);

    k_layer1<<<blocksL, TPB, 0, stream>>>(u1, row_start, csr_src, dinv, W1, b1, u2, n);
    k_layer2<<<blocksL, TPB, 0, stream>>>(u2, row_start, csr_src, dinv, W2, b2, Wfc, bfc, out, n);
}

// Round 7
// 242.786 us; speedup vs baseline: 1.0637x; 1.0637x over previous
//
#include <hip/hip_runtime.h>
#include <hip/hip_fp16.h>
#include <math.h>

// GCN, aggregate-then-transform, fused. R7: u1/u2 stored as fp16 rows padded
// to one 64B cache line (stride 32 halves) -> per-edge gather = exactly 1 line.
// Accumulation in fp32. eb packed: (src<<8) | (dst & 255).

#define TPB 256
#define BSH 8                 // 256 nodes per bucket
#define BNODES 256
#define MAXBUCK 512
#define CH 8192               // edges per partition block
#define NPW 8                 // nodes per wave in layer kernels

struct __align__(8) h4 { __half2 a, b; };   // 4 halves = 8 bytes

__global__ void k_zero(int* __restrict__ p, int n) {
    int i = blockIdx.x * blockDim.x + threadIdx.x;
    if (i < n) p[i] = 0;
}

__global__ void k_bhist(const int* __restrict__ dst, int* __restrict__ bhist,
                        int E, int nbuck) {
    __shared__ int lh[MAXBUCK];
    for (int i = threadIdx.x; i < nbuck; i += TPB) lh[i] = 0;
    __syncthreads();
    const int4* dst4 = (const int4*)dst;
    int tid = blockIdx.x * TPB + threadIdx.x;
    int stride = gridDim.x * TPB;
    for (int e4 = tid; e4 * 4 < E; e4 += stride) {
        int base = e4 * 4;
        int4 d = dst4[e4];
        if (base + 0 < E) atomicAdd(&lh[d.x >> BSH], 1);
        if (base + 1 < E) atomicAdd(&lh[d.y >> BSH], 1);
        if (base + 2 < E) atomicAdd(&lh[d.z >> BSH], 1);
        if (base + 3 < E) atomicAdd(&lh[d.w >> BSH], 1);
    }
    __syncthreads();
    for (int i = threadIdx.x; i < nbuck; i += TPB)
        if (lh[i]) atomicAdd(&bhist[i], lh[i]);
}

__global__ void k_bscan(const int* __restrict__ bhist, int* __restrict__ boff,
                        int* __restrict__ bcursor, int nbuck, int E) {
    __shared__ int sm[TPB];
    int t = threadIdx.x;
    int carry = 0;
    for (int base = 0; base < nbuck; base += TPB) {
        int i = base + t;
        int v = (i < nbuck) ? bhist[i] : 0;
        sm[t] = v;
        __syncthreads();
        for (int off = 1; off < TPB; off <<= 1) {
            int x = (t >= off) ? sm[t - off] : 0;
            __syncthreads();
            sm[t] += x;
            __syncthreads();
        }
        if (i < nbuck) { boff[i] = carry + sm[t] - v; bcursor[i] = boff[i]; }
        carry += sm[TPB - 1];
        __syncthreads();
    }
    if (t == 0) boff[nbuck] = E;
}

__global__ void k_part(const int* __restrict__ src, const int* __restrict__ dst,
                       int* __restrict__ bcursor, int* __restrict__ eb,
                       int E, int nbuck) {
    __shared__ int lh[MAXBUCK];
    __shared__ int lbase[MAXBUCK];
    int t = threadIdx.x;
    int chunk0 = blockIdx.x * CH;
    int end = min(chunk0 + CH, E);
    const int4* dst4 = (const int4*)dst;
    const int4* src4 = (const int4*)src;
    for (int i = t; i < nbuck; i += TPB) lh[i] = 0;
    __syncthreads();
    for (int e4 = chunk0 / 4 + t; e4 * 4 < end; e4 += TPB) {
        int base = e4 * 4;
        int4 d = dst4[e4];
        if (base + 0 < end) atomicAdd(&lh[d.x >> BSH], 1);
        if (base + 1 < end) atomicAdd(&lh[d.y >> BSH], 1);
        if (base + 2 < end) atomicAdd(&lh[d.z >> BSH], 1);
        if (base + 3 < end) atomicAdd(&lh[d.w >> BSH], 1);
    }
    __syncthreads();
    for (int i = t; i < nbuck; i += TPB) {
        int c = lh[i];
        lbase[i] = c ? atomicAdd(&bcursor[i], c) : 0;
        lh[i] = 0;
    }
    __syncthreads();
    for (int e4 = chunk0 / 4 + t; e4 * 4 < end; e4 += TPB) {
        int base = e4 * 4;
        int4 d = dst4[e4];
        int4 s = src4[e4];
        #define PUT(c, sv) if (base + c < end) { \
            int b = (d.sv) >> BSH; \
            int r = atomicAdd(&lh[b], 1); \
            eb[lbase[b] + r] = ((s.sv) << BSH) | ((d.sv) & (BNODES - 1)); }
        PUT(0, x) PUT(1, y) PUT(2, z) PUT(3, w)
        #undef PUT
    }
}

// per bucket: LDS counting sort -> csr_src/row_start/dinv, plus
// u1h = fp16(x*dinv), row stride 32 halves (64B), halves 18..31 zeroed.
__global__ void k_bucket(const int* __restrict__ eb, const int* __restrict__ boff,
                         const float* __restrict__ x,
                         int* __restrict__ csr_src, int* __restrict__ row_start,
                         float* __restrict__ dinv, __half* __restrict__ u1h,
                         int n, int nbuck) {
    __shared__ int lcnt[BNODES];
    __shared__ int lscan[BNODES];
    __shared__ float ldinv[BNODES];
    int b = blockIdx.x;
    int t = threadIdx.x;
    int node0 = b << BSH;
    int beg = boff[b], end = boff[b + 1];
    lcnt[t] = 0;
    __syncthreads();
    for (int i = beg + t; i < end; i += TPB)
        atomicAdd(&lcnt[eb[i] & (BNODES - 1)], 1);
    __syncthreads();
    int v = lcnt[t];
    lscan[t] = v;
    __syncthreads();
    for (int off = 1; off < TPB; off <<= 1) {
        int xx = (t >= off) ? lscan[t - off] : 0;
        __syncthreads();
        lscan[t] += xx;
        __syncthreads();
    }
    int excl = lscan[t] - v;
    int node = node0 + t;
    float dv = rsqrtf(1.0f + (float)v);
    ldinv[t] = dv;
    if (node < n) {
        row_start[node] = beg + excl;
        dinv[node] = dv;
    }
    if (b == nbuck - 1 && t == 0) row_start[n] = end;
    __syncthreads();
    lcnt[t] = excl;
    __syncthreads();
    for (int i = beg + t; i < end; i += TPB) {
        int e = eb[i];
        int p = atomicAdd(&lcnt[e & (BNODES - 1)], 1);
        csr_src[beg + p] = e >> BSH;
    }
    // u1h rows for this bucket (stride 32 halves, zero pad)
    int nn = min(BNODES, n - node0);
    int tot = nn * 32;
    const float* xb = x + (size_t)node0 * 18;
    __half* ub = u1h + (size_t)node0 * 32;
    for (int i = t; i < tot; i += TPB) {
        int nl = i >> 5, f = i & 31;
        float val = (f < 18) ? xb[nl * 18 + f] * ldinv[nl] : 0.f;
        ub[i] = __float2half_rn(val);
    }
}

// layer 1 fused: wave per node (NPW serial). 8 edges/iter; 8 lanes/edge each
// loading 4 halves (h4) of the 64B u1h row. fp32 accumulate + transform @W1.
__global__ void k_layer1(const __half* __restrict__ u1h, const int* __restrict__ row_start,
                         const int* __restrict__ csr, const float* __restrict__ dinv,
                         const float* __restrict__ W1, const float* __restrict__ b1,
                         __half* __restrict__ u2h, int n) {
    int lane = threadIdx.x & 63;
    int g = lane >> 3, q = lane & 7;
    int wid = __builtin_amdgcn_readfirstlane((int)(threadIdx.x >> 6));
    int wave = blockIdx.x * (TPB / 64) + wid;
    int f = lane & 31;
    float w1r[18];
#pragma unroll
    for (int k = 0; k < 18; ++k) w1r[k] = W1[k * 32 + f];
    float b1v = b1[f];
    int node0 = wave * NPW;
    for (int r = 0; r < NPW; ++r) {
        int node = node0 + r;
        if (node >= n) return;
        int beg = row_start[node];
        int T = row_start[node + 1] - beg + 1;   // + self (entry 0)
        float a0 = 0.f, a1 = 0.f, a2 = 0.f, a3 = 0.f;
        int it = (T + 7) >> 3;
        for (int i = 0; i < it; ++i) {
            int base = i * 8;
            int idx_l = node;
            if (lane < 8) {
                int e = base + lane;
                if (e > 0 && e < T) idx_l = csr[beg + e - 1];
            }
            int srcn = __shfl(idx_l, g, 64);
            bool valid = (base + g) < T;
            h4 v = ((const h4*)(u1h + (size_t)srcn * 32))[q];
            float2 f0 = __half22float2(v.a);
            float2 f1 = __half22float2(v.b);
            if (valid) { a0 += f0.x; a1 += f0.y; a2 += f1.x; a3 += f1.y; }
        }
#pragma unroll
        for (int m = 8; m < 64; m <<= 1) {
            a0 += __shfl_xor(a0, m, 64);
            a1 += __shfl_xor(a1, m, 64);
            a2 += __shfl_xor(a2, m, 64);
            a3 += __shfl_xor(a3, m, 64);
        }
        // lane q (g arbitrary) holds row sums for halves 4q..4q+3
        float a = 0.f;
#pragma unroll
        for (int k = 0; k < 18; ++k) {
            int sl = k >> 2;
            float rk;
            switch (k & 3) {
                case 0:  rk = __shfl(a0, sl, 64); break;
                case 1:  rk = __shfl(a1, sl, 64); break;
                case 2:  rk = __shfl(a2, sl, 64); break;
                default: rk = __shfl(a3, sl, 64); break;
            }
            a = fmaf(rk, w1r[k], a);
        }
        float di = dinv[node];
        if (lane < 32)
            u2h[(size_t)node * 32 + f] =
                __float2half_rn(fmaxf(fmaf(di, a, b1v), 0.f) * di);
    }
}

// layer 2 fused: wave per node (NPW serial). 8 edges/iter; 8 lanes/edge each
// loading 4 halves of the 64B u2h row. Transform @W2 (f_out = lane), FC, lsm.
__global__ void k_layer2(const __half* __restrict__ u2h, const int* __restrict__ row_start,
                         const int* __restrict__ csr, const float* __restrict__ dinv,
                         const float* __restrict__ W2, const float* __restrict__ b2,
                         const float* __restrict__ Wfc, const float* __restrict__ bfc,
                         float* __restrict__ out, int n) {
    int lane = threadIdx.x & 63;
    int g = lane >> 3, q = lane & 7;
    int wid = __builtin_amdgcn_readfirstlane((int)(threadIdx.x >> 6));
    int wave = blockIdx.x * (TPB / 64) + wid;
    float w2r[32];
#pragma unroll
    for (int k = 0; k < 32; ++k) w2r[k] = W2[k * 64 + lane];
    float b2v = b2[lane];
    float wf0 = Wfc[lane * 2 + 0], wf1 = Wfc[lane * 2 + 1];
    float bf0 = bfc[0], bf1 = bfc[1];
    int node0 = wave * NPW;
    for (int r = 0; r < NPW; ++r) {
        int node = node0 + r;
        if (node >= n) return;
        int beg = row_start[node];
        int T = row_start[node + 1] - beg + 1;   // + self
        float a0 = 0.f, a1 = 0.f, a2 = 0.f, a3 = 0.f;
        int it = (T + 7) >> 3;
        for (int i = 0; i < it; ++i) {
            int base = i * 8;
            int idx_l = node;
            if (lane < 8) {
                int e = base + lane;
                if (e > 0 && e < T) idx_l = csr[beg + e - 1];
            }
            int srcn = __shfl(idx_l, g, 64);
            bool valid = (base + g) < T;
            h4 v = ((const h4*)(u2h + (size_t)srcn * 32))[q];
            float2 f0 = __half22float2(v.a);
            float2 f1 = __half22float2(v.b);
            if (valid) { a0 += f0.x; a1 += f0.y; a2 += f1.x; a3 += f1.y; }
        }
#pragma unroll
        for (int m = 8; m < 64; m <<= 1) {
            a0 += __shfl_xor(a0, m, 64);
            a1 += __shfl_xor(a1, m, 64);
            a2 += __shfl_xor(a2, m, 64);
            a3 += __shfl_xor(a3, m, 64);
        }
        float a = 0.f;
#pragma unroll
        for (int k = 0; k < 32; ++k) {
            int sl = k >> 2;
            float rk;
            switch (k & 3) {
                case 0:  rk = __shfl(a0, sl, 64); break;
                case 1:  rk = __shfl(a1, sl, 64); break;
                case 2:  rk = __shfl(a2, sl, 64); break;
                default: rk = __shfl(a3, sl, 64); break;
            }
            a = fmaf(rk, w2r[k], a);
        }
        float v = fmaxf(fmaf(dinv[node], a, b2v), 0.f);
        float l0 = v * wf0;
        float l1 = v * wf1;
#pragma unroll
        for (int off = 32; off >= 1; off >>= 1) {
            l0 += __shfl_xor(l0, off, 64);
            l1 += __shfl_xor(l1, off, 64);
        }
        if (lane == 0) {
            l0 += bf0;
            l1 += bf1;
            float m2 = fmaxf(l0, l1);
            float lse = m2 + logf(expf(l0 - m2) + expf(l1 - m2));
            out[node * 2 + 0] = l0 - lse;
            out[node * 2 + 1] = l1 - lse;
        }
    }
}

extern "C" void kernel_launch(void* const* d_in, const int* in_sizes, int n_in,
                              void* d_out, int out_size, void* d_ws, size_t ws_size,
                              hipStream_t stream) {
    const float* x   = (const float*)d_in[0];
    const int*   ei  = (const int*)d_in[1];
    const float* W1  = (const float*)d_in[2];
    const float* b1  = (const float*)d_in[3];
    const float* W2  = (const float*)d_in[4];
    const float* b2  = (const float*)d_in[5];
    const float* Wfc = (const float*)d_in[6];
    const float* bfc = (const float*)d_in[7];
    float* out = (float*)d_out;

    const int n = in_sizes[0] / 18;
    const int E = in_sizes[1] / 2;
    const int* src = ei;
    const int* dst = ei + E;
    const int nbuck = (n + BNODES - 1) >> BSH;

    // ws: bhist[nbuck] | boff[nbuck+1] | bcursor[nbuck] | row_start[n+1]
    //  | dinv[n] | csr_src[E] | eb[E]  (all int/float 4B)
    //  | u1h[n*32 halves] | u2h[n*32 halves]  (2B, 8B-aligned)
    char* w = (char*)d_ws;
    int*    bhist     = (int*)w;     w += (size_t)nbuck * 4;
    int*    boff      = (int*)w;     w += (size_t)(nbuck + 1) * 4;
    int*    bcursor   = (int*)w;     w += (size_t)nbuck * 4;
    int*    row_start = (int*)w;     w += (size_t)(n + 1) * 4;
    float*  dinv      = (float*)w;   w += (size_t)n * 4;
    int*    csr_src   = (int*)w;     w += (size_t)E * 4;
    int*    eb        = (int*)w;     w += (size_t)E * 4;
    w = (char*)(((size_t)w + 63) & ~(size_t)63);
    __half* u1h       = (__half*)w;  w += (size_t)n * 32 * 2;
    w = (char*)(((size_t)w + 63) & ~(size_t)63);
    __half* u2h       = (__half*)w;  w += (size_t)n * 32 * 2;

    auto blocks = [](long long work) { return (int)((work + TPB - 1) / TPB); };

    // ---- CSR build: bucketed counting sort ----
    k_zero<<<blocks(nbuck), TPB, 0, stream>>>(bhist, nbuck);
    k_bhist<<<256, TPB, 0, stream>>>(dst, bhist, E, nbuck);
    k_bscan<<<1, TPB, 0, stream>>>(bhist, boff, bcursor, nbuck, E);
    k_part<<<(E + CH - 1) / CH, TPB, 0, stream>>>(src, dst, bcursor, eb, E, nbuck);
    k_bucket<<<nbuck, TPB, 0, stream>>>(eb, boff, x, csr_src, row_start, dinv, u1h, n, nbuck);

    const int wavesL = (n + NPW - 1) / NPW;
    const int blocksL = (wavesL + (TPB / 64) - 1) / (TPB / 64);

    k_layer1<<<blocksL, TPB, 0, stream>>>(u1h, row_start, csr_src, dinv, W1, b1, u2h, n);
    k_layer2<<<blocksL, TPB, 0, stream>>>(u2h, row_start, csr_src, dinv, W2, b2, Wfc, bfc, out, n);
}

// Round 8
// 196.529 us; speedup vs baseline: 1.3141x; 1.2354x over previous
//
#include <hip/hip_runtime.h>
#include <hip/hip_fp16.h>
#include <math.h>

// GCN, aggregate-then-transform. R8: shuffle-free agg (16 lanes/node, half2
// feature pairs, coalesced 64B row gathers) + shuffle-free transforms
// (wave-uniform scalar row loads, register weights). CSR via slab-allocated
// bucket counting sort (no global histogram/scan passes).
// eb packed: (src<<8) | (dst & 255). u rows: fp16, stride 32 halves = 64B.

#define TPB 256
#define BSH 8                 // 256 nodes per bucket
#define BNODES 256
#define MAXBUCK 512
#define CH 8192               // edges per partition block
#define NPW 8                 // nodes per wave in transform kernels
#define CAPSH 12              // slab capacity 4096 entries/bucket
#define CAP (1 << CAPSH)

__global__ void k_initcur(int* __restrict__ bcursor, int nbuck) {
    int i = blockIdx.x * blockDim.x + threadIdx.x;
    if (i < nbuck) bcursor[i] = i << CAPSH;
}

// partition edges into per-bucket slabs (chunk LDS histogram + one
// reservation atomic per (chunk,bucket)); writes are bucket-contiguous runs.
__global__ void k_part(const int* __restrict__ src, const int* __restrict__ dst,
                       int* __restrict__ bcursor, int* __restrict__ eb,
                       int E, int nbuck) {
    __shared__ int lh[MAXBUCK];
    __shared__ int lbase[MAXBUCK];
    int t = threadIdx.x;
    int chunk0 = blockIdx.x * CH;
    int end = min(chunk0 + CH, E);
    const int4* dst4 = (const int4*)dst;
    const int4* src4 = (const int4*)src;
    for (int i = t; i < nbuck; i += TPB) lh[i] = 0;
    __syncthreads();
    for (int e4 = chunk0 / 4 + t; e4 * 4 < end; e4 += TPB) {
        int base = e4 * 4;
        int4 d = dst4[e4];
        if (base + 0 < end) atomicAdd(&lh[d.x >> BSH], 1);
        if (base + 1 < end) atomicAdd(&lh[d.y >> BSH], 1);
        if (base + 2 < end) atomicAdd(&lh[d.z >> BSH], 1);
        if (base + 3 < end) atomicAdd(&lh[d.w >> BSH], 1);
    }
    __syncthreads();
    for (int i = t; i < nbuck; i += TPB) {
        int c = lh[i];
        lbase[i] = c ? atomicAdd(&bcursor[i], c) : 0;
        lh[i] = 0;
    }
    __syncthreads();
    for (int e4 = chunk0 / 4 + t; e4 * 4 < end; e4 += TPB) {
        int base = e4 * 4;
        int4 d = dst4[e4];
        int4 s = src4[e4];
        #define PUT(c, sv) if (base + c < end) { \
            int b = (d.sv) >> BSH; \
            int r = atomicAdd(&lh[b], 1); \
            int pos = lbase[b] + r; \
            if (pos < ((b + 1) << CAPSH)) \
                eb[pos] = ((s.sv) << BSH) | ((d.sv) & (BNODES - 1)); }
        PUT(0, x) PUT(1, y) PUT(2, z) PUT(3, w)
        #undef PUT
    }
}

// per bucket: LDS counting sort within slab -> csr (slab space), row_start,
// cnt, dinv, plus u1h = fp16(x*dinv) rows (stride 32 halves, pad zeroed).
__global__ void k_bucket(const int* __restrict__ eb, const int* __restrict__ bcursor,
                         const float* __restrict__ x,
                         int* __restrict__ csr, int* __restrict__ row_start,
                         int* __restrict__ cnt, float* __restrict__ dinv,
                         __half* __restrict__ u1h, int n) {
    __shared__ int lcnt[BNODES];
    __shared__ int lscan[BNODES];
    __shared__ float ldinv[BNODES];
    int b = blockIdx.x;
    int t = threadIdx.x;
    int node0 = b << BSH;
    int beg = b << CAPSH;
    int end = bcursor[b];
    lcnt[t] = 0;
    __syncthreads();
    for (int i = beg + t; i < end; i += TPB)
        atomicAdd(&lcnt[eb[i] & (BNODES - 1)], 1);
    __syncthreads();
    int v = lcnt[t];
    lscan[t] = v;
    __syncthreads();
    for (int off = 1; off < TPB; off <<= 1) {
        int xx = (t >= off) ? lscan[t - off] : 0;
        __syncthreads();
        lscan[t] += xx;
        __syncthreads();
    }
    int excl = lscan[t] - v;
    int node = node0 + t;
    float dv = rsqrtf(1.0f + (float)v);
    ldinv[t] = dv;
    if (node < n) {
        row_start[node] = beg + excl;
        cnt[node] = v;
        dinv[node] = dv;
    }
    __syncthreads();
    lcnt[t] = excl;
    __syncthreads();
    for (int i = beg + t; i < end; i += TPB) {
        int e = eb[i];
        int p = atomicAdd(&lcnt[e & (BNODES - 1)], 1);
        csr[beg + p] = e >> BSH;
    }
    // u1h rows for this bucket
    int nn = min(BNODES, n - node0);
    int tot = nn * 32;
    const float* xb = x + (size_t)node0 * 18;
    __half* ub = u1h + (size_t)node0 * 32;
    for (int i = t; i < tot; i += TPB) {
        int nl = i >> 5, f = i & 31;
        float val = (f < 18) ? xb[nl * 18 + f] * ldinv[nl] : 0.f;
        ub[i] = __float2half_rn(val);
    }
}

// agg over fp16 rows (stride 16 half2): 16 lanes per node, lane owns half2
// feature pair f2. Per edge: broadcast csr read + coalesced 64B row load.
// No cross-lane ops. Writes fp32 agg rows (stride OS floats, NW half2 valid).
template <int OS, int NW>
__global__ void k_agg(const __half2* __restrict__ uh2, const int* __restrict__ row_start,
                      const int* __restrict__ cnt, const int* __restrict__ csr,
                      float* __restrict__ agg, int n) {
    int t = blockIdx.x * blockDim.x + threadIdx.x;
    int node = t >> 4, f2 = t & 15;
    if (node >= n) return;
    int beg = row_start[node], num = cnt[node];
    float2 acc = __half22float2(uh2[(size_t)node * 16 + f2]);
    int i = 0;
    for (; i + 4 <= num; i += 4) {
        int s0 = csr[beg + i], s1 = csr[beg + i + 1];
        int s2 = csr[beg + i + 2], s3 = csr[beg + i + 3];
        float2 v0 = __half22float2(uh2[(size_t)s0 * 16 + f2]);
        float2 v1 = __half22float2(uh2[(size_t)s1 * 16 + f2]);
        float2 v2 = __half22float2(uh2[(size_t)s2 * 16 + f2]);
        float2 v3 = __half22float2(uh2[(size_t)s3 * 16 + f2]);
        acc.x += (v0.x + v1.x) + (v2.x + v3.x);
        acc.y += (v0.y + v1.y) + (v2.y + v3.y);
    }
    for (; i < num; ++i) {
        int s = csr[beg + i];
        float2 v = __half22float2(uh2[(size_t)s * 16 + f2]);
        acc.x += v.x;
        acc.y += v.y;
    }
    if (f2 < NW) *(float2*)(agg + (size_t)node * OS + 2 * f2) = acc;
}

// l1 transform: wave per NPW nodes; row via wave-uniform scalar loads,
// W1 column f in 18 VGPRs. No shuffles. Out: u2h fp16 rows.
__global__ void k_l1(const float* __restrict__ agg1, const float* __restrict__ W1,
                     const float* __restrict__ dinv, const float* __restrict__ b1,
                     __half* __restrict__ u2h, int n) {
    int lane = threadIdx.x & 63;
    int f = lane & 31;
    int wid = __builtin_amdgcn_readfirstlane((int)(threadIdx.x >> 6));
    int wave = blockIdx.x * (TPB / 64) + wid;
    float w1r[18];
#pragma unroll
    for (int k = 0; k < 18; ++k) w1r[k] = W1[k * 32 + f];
    float b1v = b1[f];
    int node0 = wave * NPW;
    for (int r = 0; r < NPW; ++r) {
        int node = node0 + r;
        if (node >= n) return;
        const float* rp = agg1 + (size_t)node * 18;
        float a = 0.f;
#pragma unroll
        for (int k = 0; k < 18; ++k) a = fmaf(rp[k], w1r[k], a);
        float di = dinv[node];
        if (lane < 32)
            u2h[(size_t)node * 32 + f] =
                __float2half_rn(fmaxf(fmaf(di, a, b1v), 0.f) * di);
    }
}

// l2 transform + head: wave per NPW nodes; row scalar, W2 col (lane) in 32
// VGPRs; FC(64->2) butterfly (only shuffles left) + log_softmax.
__global__ void k_l2_out(const float* __restrict__ agg2, const float* __restrict__ W2,
                         const float* __restrict__ dinv, const float* __restrict__ b2,
                         const float* __restrict__ Wfc, const float* __restrict__ bfc,
                         float* __restrict__ out, int n) {
    int lane = threadIdx.x & 63;
    int wid = __builtin_amdgcn_readfirstlane((int)(threadIdx.x >> 6));
    int wave = blockIdx.x * (TPB / 64) + wid;
    float w2r[32];
#pragma unroll
    for (int k = 0; k < 32; ++k) w2r[k] = W2[k * 64 + lane];
    float b2v = b2[lane];
    float wf0 = Wfc[lane * 2 + 0], wf1 = Wfc[lane * 2 + 1];
    float bf0 = bfc[0], bf1 = bfc[1];
    int node0 = wave * NPW;
    for (int r = 0; r < NPW; ++r) {
        int node = node0 + r;
        if (node >= n) return;
        const float* rp = agg2 + (size_t)node * 32;
        float a0 = 0.f, a1 = 0.f, a2 = 0.f, a3 = 0.f;
#pragma unroll
        for (int k = 0; k < 32; k += 4) {
            a0 = fmaf(rp[k],     w2r[k],     a0);
            a1 = fmaf(rp[k + 1], w2r[k + 1], a1);
            a2 = fmaf(rp[k + 2], w2r[k + 2], a2);
            a3 = fmaf(rp[k + 3], w2r[k + 3], a3);
        }
        float a = (a0 + a1) + (a2 + a3);
        float v = fmaxf(fmaf(dinv[node], a, b2v), 0.f);
        float l0 = v * wf0;
        float l1 = v * wf1;
#pragma unroll
        for (int off = 32; off >= 1; off >>= 1) {
            l0 += __shfl_xor(l0, off, 64);
            l1 += __shfl_xor(l1, off, 64);
        }
        if (lane == 0) {
            l0 += bf0;
            l1 += bf1;
            float m2 = fmaxf(l0, l1);
            float lse = m2 + logf(expf(l0 - m2) + expf(l1 - m2));
            out[node * 2 + 0] = l0 - lse;
            out[node * 2 + 1] = l1 - lse;
        }
    }
}

extern "C" void kernel_launch(void* const* d_in, const int* in_sizes, int n_in,
                              void* d_out, int out_size, void* d_ws, size_t ws_size,
                              hipStream_t stream) {
    const float* x   = (const float*)d_in[0];
    const int*   ei  = (const int*)d_in[1];
    const float* W1  = (const float*)d_in[2];
    const float* b1  = (const float*)d_in[3];
    const float* W2  = (const float*)d_in[4];
    const float* b2  = (const float*)d_in[5];
    const float* Wfc = (const float*)d_in[6];
    const float* bfc = (const float*)d_in[7];
    float* out = (float*)d_out;

    const int n = in_sizes[0] / 18;
    const int E = in_sizes[1] / 2;
    const int* src = ei;
    const int* dst = ei + E;
    const int nbuck = (n + BNODES - 1) >> BSH;

    // ws: bcursor[nbuck] | row_start[n] | cnt[n] | dinv[n]
    //  | eb[nbuck*CAP] | csr[nbuck*CAP] | agg1[n*18 f32] | agg2[n*32 f32]
    //  | u1h[n*32 h] | u2h[n*32 h]
    char* w = (char*)d_ws;
    int*    bcursor   = (int*)w;     w += (size_t)nbuck * 4;
    int*    row_start = (int*)w;     w += (size_t)n * 4;
    int*    cnt       = (int*)w;     w += (size_t)n * 4;
    float*  dinv      = (float*)w;   w += (size_t)n * 4;
    int*    eb        = (int*)w;     w += (size_t)nbuck * CAP * 4;
    int*    csr       = (int*)w;     w += (size_t)nbuck * CAP * 4;
    float*  agg1      = (float*)w;   w += (size_t)n * 18 * 4;
    float*  agg2      = (float*)w;   w += (size_t)n * 32 * 4;
    w = (char*)(((size_t)w + 63) & ~(size_t)63);
    __half* u1h       = (__half*)w;  w += (size_t)n * 32 * 2;
    w = (char*)(((size_t)w + 63) & ~(size_t)63);
    __half* u2h       = (__half*)w;  w += (size_t)n * 32 * 2;

    auto blocks = [](long long work) { return (int)((work + TPB - 1) / TPB); };

    // ---- CSR build: slab bucket sort ----
    k_initcur<<<blocks(nbuck), TPB, 0, stream>>>(bcursor, nbuck);
    k_part<<<(E + CH - 1) / CH, TPB, 0, stream>>>(src, dst, bcursor, eb, E, nbuck);
    k_bucket<<<nbuck, TPB, 0, stream>>>(eb, bcursor, x, csr, row_start, cnt, dinv, u1h, n);

    const int blocksA = blocks((long long)n * 16);
    const int wavesT = (n + NPW - 1) / NPW;
    const int blocksT = (wavesT + (TPB / 64) - 1) / (TPB / 64);

    // ---- layer 1 ----
    k_agg<18, 9><<<blocksA, TPB, 0, stream>>>((const __half2*)u1h, row_start, cnt, csr, agg1, n);
    k_l1<<<blocksT, TPB, 0, stream>>>(agg1, W1, dinv, b1, u2h, n);

    // ---- layer 2 + head ----
    k_agg<32, 16><<<blocksA, TPB, 0, stream>>>((const __half2*)u2h, row_start, cnt, csr, agg2, n);
    k_l2_out<<<blocksT, TPB, 0, stream>>>(agg2, W2, dinv, b2, Wfc, bfc, out, n);
}